// Round 6
// baseline (671.583 us; speedup 1.0000x reference)
//
#include <hip/hip_runtime.h>

// Shapes (fixed by the problem)
#define Bx 16
#define Cx 256
#define Dx 32
#define Nx 2304   // 48*48

typedef _Float16 f16;
typedef _Float16 f16x4 __attribute__((ext_vector_type(4)));
typedef _Float16 f16x8 __attribute__((ext_vector_type(8)));
typedef float    f32x4 __attribute__((ext_vector_type(4)));
typedef float    f32x16 __attribute__((ext_vector_type(16)));
typedef unsigned int u32x2 __attribute__((ext_vector_type(2)));
typedef unsigned int u32x4 __attribute__((ext_vector_type(4)));

// A,B fragment layouts (gfx950):
//  32x32x16_f16: lane holds A[m=lane%32][k=(lane/32)*8 + 0..7]  (f16x8)
//  C/D 32x32   : col=lane&31, row=(reg&3)+8*(reg>>2)+4*(lane>>5)  [verified]
#define MFMA_K16(a, b, c) __builtin_amdgcn_mfma_f32_32x32x16_f16((a), (b), (c), 0, 0, 0)
#define EXP2F(x) __builtin_amdgcn_exp2f(x)

// Repack two f16x4 B-frags of the K8 layout (j-granularity 4 per lane-half)
// into one f16x8 B-frag of the K16 layout (j-granularity 8 per lane-half).
// (R1/R2/R5-verified correct.)
__device__ __forceinline__ f16x8 swap_pack(f16x4 a, f16x4 b) {
    u32x2 au = __builtin_bit_cast(u32x2, a);
    u32x2 bu = __builtin_bit_cast(u32x2, b);
    unsigned a0 = au[0], a1 = au[1], b0 = bu[0], b1 = bu[1];
    asm("v_permlane32_swap_b32 %0, %1" : "+v"(a0), "+v"(b0));
    asm("v_permlane32_swap_b32 %0, %1" : "+v"(a1), "+v"(b1));
    u32x4 r = {a0, a1, b0, b1};
    return __builtin_bit_cast(f16x8, r);
}

// ---------------------------------------------------------------------------
// Kernel A: q/k projections -> f16 hi/lo, layout [b][n][d] (d contiguous).
// q pre-scaled by 1/ln2 so softmax uses exp2 directly. (R5-passing, unchanged)
// ---------------------------------------------------------------------------
__global__ __launch_bounds__(256) void qk_proj(
    const float* __restrict__ x,
    const float* __restrict__ Wq, const float* __restrict__ bq,
    const float* __restrict__ Wk, const float* __restrict__ bk,
    f16* __restrict__ qhi, f16* __restrict__ qlo,
    f16* __restrict__ khi, f16* __restrict__ klo) {
    int bid = blockIdx.x;
    int nt = bid % 9;  bid /= 9;
    int dc = bid % 4;  bid /= 4;
    int b  = bid % Bx; bid /= Bx;
    int qk = bid;  // 0 -> q, 1 -> k
    const float* Wm   = qk ? Wk : Wq;
    const float* bias = qk ? bk : bq;
    f16* dhi          = qk ? khi : qhi;
    f16* dlo          = qk ? klo : qlo;
    float sc          = qk ? 1.0f : 1.4426950408889634f;  // q *= 1/ln2

    int n  = nt * 256 + threadIdx.x;
    int d0 = dc * 8;
    float acc[8];
#pragma unroll
    for (int dd = 0; dd < 8; ++dd) acc[dd] = bias[d0 + dd];

    const float* xcol = x + (size_t)b * Cx * Nx + n;
    for (int c = 0; c < Cx; ++c) {
        float xv = xcol[(size_t)c * Nx];
#pragma unroll
        for (int dd = 0; dd < 8; ++dd)
            acc[dd] += Wm[(d0 + dd) * Cx + c] * xv;
    }
    f16x8 hi, lo;
#pragma unroll
    for (int dd = 0; dd < 8; ++dd) {
        float a = acc[dd] * sc;
        f16 h = (f16)a;
        hi[dd] = h;
        lo[dd] = (f16)(a - (float)h);
    }
    size_t base = ((size_t)b * Nx + n) * Dx + d0;
    *(f16x8*)(dhi + base) = hi;
    *(f16x8*)(dlo + base) = lo;
}

// ---------------------------------------------------------------------------
// Kernel B: v projection -> f16 hi/lo, layout [b][c][n]. (R5-passing, unchanged)
// ---------------------------------------------------------------------------
__global__ __launch_bounds__(256) void v_proj(
    const float* __restrict__ x,
    const float* __restrict__ Wv, const float* __restrict__ bv,
    f16* __restrict__ vhi, f16* __restrict__ vlo) {
    __shared__ float sx[Cx * 16];
    int bid = blockIdx.x;
    int nt = bid % (Nx / 16);
    int b  = bid / (Nx / 16);
    int n0 = nt * 16;
    int t  = threadIdx.x;

    for (int r = 0; r < 16; ++r) {
        int f = r * 256 + t;
        int c = f >> 4, nn = f & 15;
        sx[f] = x[((size_t)b * Cx + c) * Nx + n0 + nn];
    }
    __syncthreads();

    float acc[16];
    float bvv = bv[t];
#pragma unroll
    for (int nn = 0; nn < 16; ++nn) acc[nn] = bvv;

    const float* wrow = Wv + (size_t)t * Cx;
    for (int c = 0; c < Cx; ++c) {
        float wv = wrow[c];
        const float4* sxr = (const float4*)&sx[c * 16];
#pragma unroll
        for (int g = 0; g < 4; ++g) {
            float4 xv = sxr[g];
            acc[g * 4 + 0] += wv * xv.x;
            acc[g * 4 + 1] += wv * xv.y;
            acc[g * 4 + 2] += wv * xv.z;
            acc[g * 4 + 3] += wv * xv.w;
        }
    }
    f16x8 h0, l0, h1, l1;
#pragma unroll
    for (int nn = 0; nn < 8; ++nn) {
        f16 h = (f16)acc[nn];
        h0[nn] = h; l0[nn] = (f16)(acc[nn] - (float)h);
    }
#pragma unroll
    for (int nn = 0; nn < 8; ++nn) {
        f16 h = (f16)acc[8 + nn];
        h1[nn] = h; l1[nn] = (f16)(acc[8 + nn] - (float)h);
    }
    size_t base = ((size_t)b * Cx + t) * Nx + n0;
    *(f16x8*)(vhi + base)     = h0;
    *(f16x8*)(vhi + base + 8) = h1;
    *(f16x8*)(vlo + base)     = l0;
    *(f16x8*)(vlo + base + 8) = l1;
}

// ---------------------------------------------------------------------------
// Kernel C: softmax column sums  s[b][j] = sum_i exp2(E[i,j]).
// 4 waves per block, LDS partial reduce. (R5-passing, unchanged)
// ---------------------------------------------------------------------------
__global__ __launch_bounds__(256, 4) void col_stats(
    const f16* __restrict__ qhi, const f16* __restrict__ qlo,
    const f16* __restrict__ khi, const f16* __restrict__ klo,
    float* __restrict__ s) {
    __shared__ float part[4][32];
    int jt = blockIdx.x % 72;
    int b  = blockIdx.x / 72;
    int j0 = jt * 32;
    int t  = threadIdx.x;
    int w  = t >> 6;              // wave id 0..3
    int il = t & 31, h = (t >> 5) & 1;

    f16x8 kh[2], kl[2];
#pragma unroll
    for (int ks = 0; ks < 2; ++ks) {
        size_t off = ((size_t)b * Nx + j0 + il) * Dx + h * 8 + ks * 16;
        kh[ks] = *(const f16x8*)(khi + off);
        kl[ks] = *(const f16x8*)(klo + off);
    }
    f32x16 sacc = {};
    for (int it = w * 18; it < w * 18 + 18; ++it) {
        f16x8 qh[2], ql[2];
#pragma unroll
        for (int ks = 0; ks < 2; ++ks) {
            size_t off = ((size_t)b * Nx + it * 32 + il) * Dx + h * 8 + ks * 16;
            qh[ks] = *(const f16x8*)(qhi + off);
            ql[ks] = *(const f16x8*)(qlo + off);
        }
        f32x16 e = {};
        __builtin_amdgcn_s_setprio(1);
        e = MFMA_K16(kh[0], qh[0], e);
        e = MFMA_K16(kh[0], ql[0], e);
        e = MFMA_K16(kl[0], qh[0], e);
        e = MFMA_K16(kh[1], qh[1], e);
        e = MFMA_K16(kh[1], ql[1], e);
        e = MFMA_K16(kl[1], qh[1], e);
        __builtin_amdgcn_s_setprio(0);
#pragma unroll
        for (int r = 0; r < 16; ++r) sacc[r] += EXP2F(e[r]);
    }
#pragma unroll
    for (int r = 0; r < 16; ++r) {
        float v = sacc[r];
        for (int msk = 1; msk <= 16; msk <<= 1) v += __shfl_xor(v, msk);
        if (il == 0) part[w][(r & 3) + 8 * (r >> 2) + 4 * h] = v;
    }
    __syncthreads();
    if (t < 32)
        s[(size_t)b * Nx + j0 + t] =
            part[0][t] + part[1][t] + part[2][t] + part[3][t];
}

// ---------------------------------------------------------------------------
// Kernel D: main.  R6: occupancy fix — 4 waves/block = (itile x j-half).
// Each wave: ONE 32-i subtile, 36 j-tiles, 2 c-groups. Per-wave live set
// ~80 VGPR (acc 32 + q 16 + K 32 + V 32 overlapped by regalloc) -> ~6
// waves/SIMD VGPR-cap vs R5's 1.5 resident. launch_bounds(256,3) gives a
// 170-reg budget: NO forced spill (prime suspect in the R3 failures).
// Partials combine by addition via one padded-LDS exchange (softmax denom
// is global and precomputed). All R5-verified machinery retained.
// grid: Bx * 36 * 4 = 2304 blocks, 256 threads.
// ---------------------------------------------------------------------------
__global__ __launch_bounds__(256, 3) void attn_out(
    const f16* __restrict__ qhi, const f16* __restrict__ qlo,
    const f16* __restrict__ khi, const f16* __restrict__ klo,
    const f16* __restrict__ vhi, const f16* __restrict__ vlo,
    const float* __restrict__ s, const float* __restrict__ x,
    const float* __restrict__ gamma, float* __restrict__ out) {
    __shared__ __align__(16) float rs[Nx];     // 9216 B: 1/s for this batch
    __shared__ float red[2][64][33];           // 16896 B, padded (stride 33)
    int blk = blockIdx.x;
    int w4   = blk & 3;  blk >>= 2;     // c-quarter
    int it64 = blk % 36;
    int b    = blk / 36;
    int i0   = it64 * 64;
    int c0   = w4 * 64;
    int t = threadIdx.x;
    int wid  = t >> 6;                  // wave 0..3
    int lane = t & 63;
    int il = t & 31, h = (t >> 5) & 1;
    int itile = wid & 1;                // which 32-i subtile
    int jh    = wid >> 1;               // which j-half (0..1)

    {   // stage reciprocal sums (256 threads)
        const f32x4* s4 = (const f32x4*)(s + (size_t)b * Nx);
        f32x4* rs4 = (f32x4*)rs;
        for (int r = t; r < Nx / 4; r += 256) {
            f32x4 v = s4[r];
            rs4[r] = (f32x4){1.0f / v[0], 1.0f / v[1], 1.0f / v[2], 1.0f / v[3]};
        }
    }
    __syncthreads();

    int i32 = i0 + itile * 32;
    // Q as B-operand for E^T (this wave's itile only), hoisted
    f16x8 qh[2], ql[2];
#pragma unroll
    for (int ks = 0; ks < 2; ++ks) {
        size_t off = ((size_t)b * Nx + i32 + il) * Dx + h * 8 + ks * 16;
        qh[ks] = *(const f16x8*)(qhi + off);
        ql[ks] = *(const f16x8*)(qlo + off);
    }

    f32x16 acc[2];   // [cg] : out^T tile [c 32][i 32] partial (this j-half)
    acc[0] = (f32x16){};
    acc[1] = (f32x16){};

    // per-wave base pointers: j window = [jh*1152, jh*1152+1152)
    int jb = jh * 36 * 32;
    const f16* kph = khi + ((size_t)b * Nx + jb + il) * Dx + h * 8;
    const f16* kpl = klo + ((size_t)b * Nx + jb + il) * Dx + h * 8;
    const f16* vph = vhi + ((size_t)b * Cx + c0 + il) * Nx + jb + h * 8;
    const f16* vpl = vlo + ((size_t)b * Cx + c0 + il) * Nx + jb + h * 8;

    // K register double-buffer, V register single-buffer (late prefetch)
    f16x8 kh[2][2], kl[2][2];    // [buf][ks]
    f16x8 vh8[2][2], vl8[2][2];  // [cg][gp]

    // prologue: K tile 0 into buf 0, V tile 0
#pragma unroll
    for (int ks = 0; ks < 2; ++ks) {
        kh[0][ks] = *(const f16x8*)(kph + ks * 16);
        kl[0][ks] = *(const f16x8*)(kpl + ks * 16);
    }
#pragma unroll
    for (int cg = 0; cg < 2; ++cg)
#pragma unroll
        for (int gp = 0; gp < 2; ++gp) {
            size_t voff = (size_t)cg * 32 * Nx + gp * 16;
            vh8[cg][gp] = *(const f16x8*)(vph + voff);
            vl8[cg][gp] = *(const f16x8*)(vpl + voff);
        }

#pragma unroll 2
    for (int jt = 0; jt < 36; ++jt) {
        int cur = jt & 1, nxt = cur ^ 1;
        int j0  = jb + jt * 32;          // global j for rs indexing
        // ---- prefetch K(jt+1) into the other buffer (wraps harmlessly) ----
        int kn = (jt + 1 < 36) ? (jt + 1) * 1024 : 0;  // 32*Dx f16 per j-tile
#pragma unroll
        for (int ks = 0; ks < 2; ++ks) {
            kh[nxt][ks] = *(const f16x8*)(kph + kn + ks * 16);
            kl[nxt][ks] = *(const f16x8*)(kpl + kn + ks * 16);
        }
        // ---- E^T tile: rows j, cols i ----
        f32x16 e = {};
        __builtin_amdgcn_s_setprio(1);
        e = MFMA_K16(kh[cur][0], qh[0], e);
        e = MFMA_K16(kh[cur][0], ql[0], e);
        e = MFMA_K16(kl[cur][0], qh[0], e);
        e = MFMA_K16(kh[cur][1], qh[1], e);
        e = MFMA_K16(kh[cur][1], ql[1], e);
        e = MFMA_K16(kl[cur][1], qh[1], e);
        __builtin_amdgcn_s_setprio(0);
        // ---- P^T = exp2(E^T) * rs[j]; reg 4g+jj holds j = j0+jj+8g+4h ----
        f16x4 ph4[4], pl4[4];
#pragma unroll
        for (int g = 0; g < 4; ++g) {
            f32x4 rsv = *(const f32x4*)&rs[j0 + 8 * g + 4 * h];
#pragma unroll
            for (int jj = 0; jj < 4; ++jj) {
                float p = EXP2F(e[4 * g + jj]) * rsv[jj];
                f16 hh = (f16)p;
                ph4[g][jj] = hh;
                pl4[g][jj] = (f16)(p - (float)hh);
            }
        }
        // ---- repack K8 frag pairs -> K16 frags ----
        f16x8 phK[2], plK[2];
#pragma unroll
        for (int gp = 0; gp < 2; ++gp) {
            phK[gp] = swap_pack(ph4[2 * gp], ph4[2 * gp + 1]);
            plK[gp] = swap_pack(pl4[2 * gp], pl4[2 * gp + 1]);
        }
        // ---- PV: acc[c][i] += V[c][j16-block gp] * P^T[j16-block gp][i] ----
        __builtin_amdgcn_s_setprio(1);
#pragma unroll
        for (int cg = 0; cg < 2; ++cg)
#pragma unroll
            for (int gp = 0; gp < 2; ++gp) {
                acc[cg] = MFMA_K16(vh8[cg][gp], phK[gp], acc[cg]);
                acc[cg] = MFMA_K16(vh8[cg][gp], plK[gp], acc[cg]);
                acc[cg] = MFMA_K16(vl8[cg][gp], phK[gp], acc[cg]);
            }
        __builtin_amdgcn_s_setprio(0);
        // ---- late-issue V(jt+1) into the same registers (after last PV read)
        int vn = (jt + 1 < 36) ? (jt + 1) * 32 : 0;
#pragma unroll
        for (int cg = 0; cg < 2; ++cg)
#pragma unroll
            for (int gp = 0; gp < 2; ++gp) {
                size_t voff = (size_t)cg * 32 * Nx + vn + gp * 16;
                vh8[cg][gp] = *(const f16x8*)(vph + voff);
                vl8[cg][gp] = *(const f16x8*)(vpl + voff);
            }
    }

    // ---- combine j-halves via LDS, then store (jh==0 waves) ----
    if (jh == 1) {
#pragma unroll
        for (int cg = 0; cg < 2; ++cg)
#pragma unroll
            for (int r = 0; r < 16; ++r)
                red[itile][lane][cg * 16 + r] = acc[cg][r];
    }
    __syncthreads();
    if (jh == 0) {
        float gm = gamma[0];
#pragma unroll
        for (int cg = 0; cg < 2; ++cg)
#pragma unroll
            for (int r = 0; r < 16; ++r) {
                int c = c0 + cg * 32 + (r & 3) + 8 * (r >> 2) + 4 * h;
                int i = i32 + il;
                size_t idx = ((size_t)b * Cx + c) * Nx + i;
                out[idx] = x[idx] + gm * (acc[cg][r] + red[itile][lane][cg * 16 + r]);
            }
    }
}

// ---------------------------------------------------------------------------
extern "C" void kernel_launch(void* const* d_in, const int* in_sizes, int n_in,
                              void* d_out, int out_size, void* d_ws, size_t ws_size,
                              hipStream_t stream) {
    const float* x     = (const float*)d_in[0];
    const float* Wq    = (const float*)d_in[1];
    const float* bq    = (const float*)d_in[2];
    const float* Wk    = (const float*)d_in[3];
    const float* bk    = (const float*)d_in[4];
    const float* Wv    = (const float*)d_in[5];
    const float* bv    = (const float*)d_in[6];
    const float* gamma = (const float*)d_in[7];
    float* out = (float*)d_out;

    const size_t QK = (size_t)Bx * Nx * Dx;
    const size_t VN = (size_t)Bx * Cx * Nx;
    f16* qhi = (f16*)d_ws;
    f16* qlo = qhi + QK;
    f16* khi = qlo + QK;
    f16* klo = khi + QK;
    f16* vhi = klo + QK;
    f16* vlo = vhi + VN;
    float* s = (float*)(vlo + VN);

    qk_proj  <<<2 * Bx * 4 * 9, 256, 0, stream>>>(x, Wq, bq, Wk, bk, qhi, qlo, khi, klo);
    v_proj   <<<Bx * (Nx / 16), 256, 0, stream>>>(x, Wv, bv, vhi, vlo);
    col_stats<<<Bx * 72,        256, 0, stream>>>(qhi, qlo, khi, klo, s);
    attn_out <<<Bx * 36 * 4,    256, 0, stream>>>(qhi, qlo, khi, klo, vhi, vlo, s, x, gamma, out);
}

// Round 7
// 535.694 us; speedup vs baseline: 1.2537x; 1.2537x over previous
//
#include <hip/hip_runtime.h>

// Shapes (fixed by the problem)
#define Bx 16
#define Cx 256
#define Dx 32
#define Nx 2304   // 48*48

typedef _Float16 f16;
typedef _Float16 f16x4 __attribute__((ext_vector_type(4)));
typedef _Float16 f16x8 __attribute__((ext_vector_type(8)));
typedef float    f32x4 __attribute__((ext_vector_type(4)));
typedef float    f32x16 __attribute__((ext_vector_type(16)));
typedef unsigned int u32x2 __attribute__((ext_vector_type(2)));
typedef unsigned int u32x4 __attribute__((ext_vector_type(4)));

// A,B fragment layouts (gfx950):
//  32x32x16_f16: lane holds A[m=lane%32][k=(lane/32)*8 + 0..7]  (f16x8)
//  C/D 32x32   : col=lane&31, row=(reg&3)+8*(reg>>2)+4*(lane>>5)  [verified]
#define MFMA_K16(a, b, c) __builtin_amdgcn_mfma_f32_32x32x16_f16((a), (b), (c), 0, 0, 0)
#define EXP2F(x) __builtin_amdgcn_exp2f(x)

// Repack two f16x4 B-frags of the K8 layout (j-granularity 4 per lane-half)
// into one f16x8 B-frag of the K16 layout (j-granularity 8 per lane-half).
// (R1/R2/R5-verified correct.)
__device__ __forceinline__ f16x8 swap_pack(f16x4 a, f16x4 b) {
    u32x2 au = __builtin_bit_cast(u32x2, a);
    u32x2 bu = __builtin_bit_cast(u32x2, b);
    unsigned a0 = au[0], a1 = au[1], b0 = bu[0], b1 = bu[1];
    asm("v_permlane32_swap_b32 %0, %1" : "+v"(a0), "+v"(b0));
    asm("v_permlane32_swap_b32 %0, %1" : "+v"(a1), "+v"(b1));
    u32x4 r = {a0, a1, b0, b1};
    return __builtin_bit_cast(f16x8, r);
}

// ---------------------------------------------------------------------------
// Kernel A: q/k projections -> f16 hi/lo, layout [b][n][d] (d contiguous).
// R7: q and k FUSED in one pass over x (halves x traffic: 302 -> 151 MB).
// q pre-scaled by 1/ln2 so softmax uses exp2 directly.
// grid: Bx * 4 * 9 = 576 blocks, 256 threads.
// ---------------------------------------------------------------------------
__global__ __launch_bounds__(256) void qk_proj(
    const float* __restrict__ x,
    const float* __restrict__ Wq, const float* __restrict__ bq,
    const float* __restrict__ Wk, const float* __restrict__ bk,
    f16* __restrict__ qhi, f16* __restrict__ qlo,
    f16* __restrict__ khi, f16* __restrict__ klo) {
    int bid = blockIdx.x;
    int nt = bid % 9;  bid /= 9;
    int dc = bid % 4;  bid /= 4;
    int b  = bid;                     // 0..15

    int n  = nt * 256 + threadIdx.x;
    int d0 = dc * 8;
    float aq[8], ak[8];
#pragma unroll
    for (int dd = 0; dd < 8; ++dd) { aq[dd] = bq[d0 + dd]; ak[dd] = bk[d0 + dd]; }

    const float* xcol = x + (size_t)b * Cx * Nx + n;
    const float* wq0  = Wq + (size_t)d0 * Cx;
    const float* wk0  = Wk + (size_t)d0 * Cx;
    for (int c = 0; c < Cx; ++c) {
        float xv = xcol[(size_t)c * Nx];
#pragma unroll
        for (int dd = 0; dd < 8; ++dd) {
            aq[dd] += wq0[dd * Cx + c] * xv;
            ak[dd] += wk0[dd * Cx + c] * xv;
        }
    }
    const float SC = 1.4426950408889634f;  // 1/ln2 on q
    f16x8 qh, ql, kh, kl;
#pragma unroll
    for (int dd = 0; dd < 8; ++dd) {
        float a = aq[dd] * SC;
        f16 h = (f16)a;
        qh[dd] = h; ql[dd] = (f16)(a - (float)h);
        float kk = ak[dd];
        f16 hk = (f16)kk;
        kh[dd] = hk; kl[dd] = (f16)(kk - (float)hk);
    }
    size_t base = ((size_t)b * Nx + n) * Dx + d0;
    *(f16x8*)(qhi + base) = qh;
    *(f16x8*)(qlo + base) = ql;
    *(f16x8*)(khi + base) = kh;
    *(f16x8*)(klo + base) = kl;
}

// ---------------------------------------------------------------------------
// Kernel B: v projection -> f16 hi/lo, layout [b][c][n]. (R5-passing, unchanged)
// ---------------------------------------------------------------------------
__global__ __launch_bounds__(256) void v_proj(
    const float* __restrict__ x,
    const float* __restrict__ Wv, const float* __restrict__ bv,
    f16* __restrict__ vhi, f16* __restrict__ vlo) {
    __shared__ float sx[Cx * 16];
    int bid = blockIdx.x;
    int nt = bid % (Nx / 16);
    int b  = bid / (Nx / 16);
    int n0 = nt * 16;
    int t  = threadIdx.x;

    for (int r = 0; r < 16; ++r) {
        int f = r * 256 + t;
        int c = f >> 4, nn = f & 15;
        sx[f] = x[((size_t)b * Cx + c) * Nx + n0 + nn];
    }
    __syncthreads();

    float acc[16];
    float bvv = bv[t];
#pragma unroll
    for (int nn = 0; nn < 16; ++nn) acc[nn] = bvv;

    const float* wrow = Wv + (size_t)t * Cx;
    for (int c = 0; c < Cx; ++c) {
        float wv = wrow[c];
        const float4* sxr = (const float4*)&sx[c * 16];
#pragma unroll
        for (int g = 0; g < 4; ++g) {
            float4 xv = sxr[g];
            acc[g * 4 + 0] += wv * xv.x;
            acc[g * 4 + 1] += wv * xv.y;
            acc[g * 4 + 2] += wv * xv.z;
            acc[g * 4 + 3] += wv * xv.w;
        }
    }
    f16x8 h0, l0, h1, l1;
#pragma unroll
    for (int nn = 0; nn < 8; ++nn) {
        f16 h = (f16)acc[nn];
        h0[nn] = h; l0[nn] = (f16)(acc[nn] - (float)h);
    }
#pragma unroll
    for (int nn = 0; nn < 8; ++nn) {
        f16 h = (f16)acc[8 + nn];
        h1[nn] = h; l1[nn] = (f16)(acc[8 + nn] - (float)h);
    }
    size_t base = ((size_t)b * Cx + t) * Nx + n0;
    *(f16x8*)(vhi + base)     = h0;
    *(f16x8*)(vhi + base + 8) = h1;
    *(f16x8*)(vlo + base)     = l0;
    *(f16x8*)(vlo + base + 8) = l1;
}

// ---------------------------------------------------------------------------
// Kernel C: softmax column sums  s[b][j] = sum_i exp2(E[i,j]).
// 4 waves per block, LDS partial reduce. (R5-passing, unchanged)
// ---------------------------------------------------------------------------
__global__ __launch_bounds__(256, 4) void col_stats(
    const f16* __restrict__ qhi, const f16* __restrict__ qlo,
    const f16* __restrict__ khi, const f16* __restrict__ klo,
    float* __restrict__ s) {
    __shared__ float part[4][32];
    int jt = blockIdx.x % 72;
    int b  = blockIdx.x / 72;
    int j0 = jt * 32;
    int t  = threadIdx.x;
    int w  = t >> 6;              // wave id 0..3
    int il = t & 31, h = (t >> 5) & 1;

    f16x8 kh[2], kl[2];
#pragma unroll
    for (int ks = 0; ks < 2; ++ks) {
        size_t off = ((size_t)b * Nx + j0 + il) * Dx + h * 8 + ks * 16;
        kh[ks] = *(const f16x8*)(khi + off);
        kl[ks] = *(const f16x8*)(klo + off);
    }
    f32x16 sacc = {};
    for (int it = w * 18; it < w * 18 + 18; ++it) {
        f16x8 qh[2], ql[2];
#pragma unroll
        for (int ks = 0; ks < 2; ++ks) {
            size_t off = ((size_t)b * Nx + it * 32 + il) * Dx + h * 8 + ks * 16;
            qh[ks] = *(const f16x8*)(qhi + off);
            ql[ks] = *(const f16x8*)(qlo + off);
        }
        f32x16 e = {};
        __builtin_amdgcn_s_setprio(1);
        e = MFMA_K16(kh[0], qh[0], e);
        e = MFMA_K16(kh[0], ql[0], e);
        e = MFMA_K16(kl[0], qh[0], e);
        e = MFMA_K16(kh[1], qh[1], e);
        e = MFMA_K16(kh[1], ql[1], e);
        e = MFMA_K16(kl[1], qh[1], e);
        __builtin_amdgcn_s_setprio(0);
#pragma unroll
        for (int r = 0; r < 16; ++r) sacc[r] += EXP2F(e[r]);
    }
#pragma unroll
    for (int r = 0; r < 16; ++r) {
        float v = sacc[r];
        for (int msk = 1; msk <= 16; msk <<= 1) v += __shfl_xor(v, msk);
        if (il == 0) part[w][(r & 3) + 8 * (r >> 2) + 4 * h] = v;
    }
    __syncthreads();
    if (t < 32)
        s[(size_t)b * Nx + j0 + t] =
            part[0][t] + part[1][t] + part[2][t] + part[3][t];
}

// ---------------------------------------------------------------------------
// Kernel D: main.  R7 = R5 shape (128 thr, 2 waves jh-split, 2 itiles/wave)
// + T15 2-deep E-pipeline: pe[itile] holds E(jt) computed during iter jt-1.
// Per iter: pack(jt) [VALU] || E(jt+1) [MFMA, independent] || PV(jt) [MFMA].
// K prefetch distance 2 (~800 cy cover), V late-issue now covered by a full
// pack+E phase. Math identical to R5 (pure reorder; jt=35's E is discarded).
// grid: Bx * 36 * 4 = 2304 blocks, 128 threads.
// ---------------------------------------------------------------------------
__global__ __launch_bounds__(128, 2) void attn_out(
    const f16* __restrict__ qhi, const f16* __restrict__ qlo,
    const f16* __restrict__ khi, const f16* __restrict__ klo,
    const f16* __restrict__ vhi, const f16* __restrict__ vlo,
    const float* __restrict__ s, const float* __restrict__ x,
    const float* __restrict__ gamma, float* __restrict__ out) {
    __shared__ __align__(16) float rs[Nx];     // 9216 B
    __shared__ float red[2][64][33];           // 16896 B, padded
    int blk = blockIdx.x;
    int w4   = blk & 3;  blk >>= 2;     // c-quarter
    int it64 = blk % 36;
    int b    = blk / 36;
    int i0   = it64 * 64;
    int c0   = w4 * 64;
    int t = threadIdx.x;
    int jh   = t >> 6;                  // wave id = j-half (0..1)
    int lane = t & 63;
    int il = t & 31, h = (t >> 5) & 1;

    {   // stage reciprocal sums (128 threads)
        const f32x4* s4 = (const f32x4*)(s + (size_t)b * Nx);
        f32x4* rs4 = (f32x4*)rs;
        for (int r = t; r < Nx / 4; r += 128) {
            f32x4 v = s4[r];
            rs4[r] = (f32x4){1.0f / v[0], 1.0f / v[1], 1.0f / v[2], 1.0f / v[3]};
        }
    }
    __syncthreads();

    // Q as B-operand for E^T, both i-subtiles, hoisted
    f16x8 qh[2][2], ql[2][2];   // [itile][ks]
#pragma unroll
    for (int itile = 0; itile < 2; ++itile)
#pragma unroll
        for (int ks = 0; ks < 2; ++ks) {
            size_t off = ((size_t)b * Nx + i0 + itile * 32 + il) * Dx + h * 8 + ks * 16;
            qh[itile][ks] = *(const f16x8*)(qhi + off);
            ql[itile][ks] = *(const f16x8*)(qlo + off);
        }

    f32x16 acc[2][2];  // [itile][cg]
#pragma unroll
    for (int a = 0; a < 2; ++a)
#pragma unroll
        for (int cgi = 0; cgi < 2; ++cgi) acc[a][cgi] = (f32x16){};

    int jb = jh * 36 * 32;
    const f16* kph = khi + ((size_t)b * Nx + jb + il) * Dx + h * 8;
    const f16* kpl = klo + ((size_t)b * Nx + jb + il) * Dx + h * 8;
    const f16* vph = vhi + ((size_t)b * Cx + c0 + il) * Nx + jb + h * 8;
    const f16* vpl = vlo + ((size_t)b * Cx + c0 + il) * Nx + jb + h * 8;

    // K double-buffer (K(j) lives in buf j&1), V single-buffer
    f16x8 kh[2][2], kl[2][2];    // [buf][ks]
    f16x8 vh8[2][2], vl8[2][2];  // [cg][gp]

    // prologue: K0 -> buf0, K1 -> buf1, V0
#pragma unroll
    for (int ks = 0; ks < 2; ++ks) {
        kh[0][ks] = *(const f16x8*)(kph + ks * 16);
        kl[0][ks] = *(const f16x8*)(kpl + ks * 16);
        kh[1][ks] = *(const f16x8*)(kph + 1024 + ks * 16);
        kl[1][ks] = *(const f16x8*)(kpl + 1024 + ks * 16);
    }
#pragma unroll
    for (int cg = 0; cg < 2; ++cg)
#pragma unroll
        for (int gp = 0; gp < 2; ++gp) {
            size_t voff = (size_t)cg * 32 * Nx + gp * 16;
            vh8[cg][gp] = *(const f16x8*)(vph + voff);
            vl8[cg][gp] = *(const f16x8*)(vpl + voff);
        }

    // prologue: E(0) for both itiles into pe[]
    f32x16 pe[2];
#pragma unroll
    for (int itile = 0; itile < 2; ++itile) {
        f32x16 e = {};
        e = MFMA_K16(kh[0][0], qh[itile][0], e);
        e = MFMA_K16(kh[0][0], ql[itile][0], e);
        e = MFMA_K16(kl[0][0], qh[itile][0], e);
        e = MFMA_K16(kh[0][1], qh[itile][1], e);
        e = MFMA_K16(kh[0][1], ql[itile][1], e);
        e = MFMA_K16(kl[0][1], qh[itile][1], e);
        pe[itile] = e;
    }

#pragma unroll 2
    for (int jt = 0; jt < 36; ++jt) {
        int cur = jt & 1, nxt = cur ^ 1;     // K(jt)=buf cur (dead), K(jt+1)=buf nxt
        int j0  = jb + jt * 32;
        // ---- issue K(jt+2) into buf cur (K(jt) fully consumed last iter) ----
        int kn = (jt + 2 < 36) ? (jt + 2) * 1024 : 0;
#pragma unroll
        for (int ks = 0; ks < 2; ++ks) {
            kh[cur][ks] = *(const f16x8*)(kph + kn + ks * 16);
            kl[cur][ks] = *(const f16x8*)(kpl + kn + ks * 16);
        }
#pragma unroll
        for (int itile = 0; itile < 2; ++itile) {
            // ---- pack P(jt) from pe[itile]: exp2 * rs, f16 hi/lo, K16 frags ----
            f16x4 ph4[4], pl4[4];
#pragma unroll
            for (int g = 0; g < 4; ++g) {
                f32x4 rsv = *(const f32x4*)&rs[j0 + 8 * g + 4 * h];
#pragma unroll
                for (int jj = 0; jj < 4; ++jj) {
                    float p = EXP2F(pe[itile][4 * g + jj]) * rsv[jj];
                    f16 hh = (f16)p;
                    ph4[g][jj] = hh;
                    pl4[g][jj] = (f16)(p - (float)hh);
                }
            }
            f16x8 phK[2], plK[2];
#pragma unroll
            for (int gp = 0; gp < 2; ++gp) {
                phK[gp] = swap_pack(ph4[2 * gp], ph4[2 * gp + 1]);
                plK[gp] = swap_pack(pl4[2 * gp], pl4[2 * gp + 1]);
            }
            __builtin_amdgcn_s_setprio(1);
            // ---- E(jt+1): independent MFMA chain, overlaps PV below ----
            {
                f32x16 e = {};
                e = MFMA_K16(kh[nxt][0], qh[itile][0], e);
                e = MFMA_K16(kh[nxt][0], ql[itile][0], e);
                e = MFMA_K16(kl[nxt][0], qh[itile][0], e);
                e = MFMA_K16(kh[nxt][1], qh[itile][1], e);
                e = MFMA_K16(kh[nxt][1], ql[itile][1], e);
                e = MFMA_K16(kl[nxt][1], qh[itile][1], e);
                pe[itile] = e;   // jt=35 writes junk (K wrapped); never packed
            }
            // ---- PV(jt): acc += V * P^T ----
#pragma unroll
            for (int cg = 0; cg < 2; ++cg)
#pragma unroll
                for (int gp = 0; gp < 2; ++gp) {
                    acc[itile][cg] = MFMA_K16(vh8[cg][gp], phK[gp], acc[itile][cg]);
                    acc[itile][cg] = MFMA_K16(vh8[cg][gp], plK[gp], acc[itile][cg]);
                    acc[itile][cg] = MFMA_K16(vl8[cg][gp], phK[gp], acc[itile][cg]);
                }
            __builtin_amdgcn_s_setprio(0);
        }
        // ---- late-issue V(jt+1); consumed after next iter's pack+E ----
        int vn = (jt + 1 < 36) ? (jt + 1) * 32 : 0;
#pragma unroll
        for (int cg = 0; cg < 2; ++cg)
#pragma unroll
            for (int gp = 0; gp < 2; ++gp) {
                size_t voff = (size_t)cg * 32 * Nx + vn + gp * 16;
                vh8[cg][gp] = *(const f16x8*)(vph + voff);
                vl8[cg][gp] = *(const f16x8*)(vpl + voff);
            }
    }

    // ---- combine j-halves via LDS, then store (jh==0 wave) ----
    if (jh == 1) {
#pragma unroll
        for (int itile = 0; itile < 2; ++itile)
#pragma unroll
            for (int cg = 0; cg < 2; ++cg)
#pragma unroll
                for (int r = 0; r < 16; ++r)
                    red[itile][lane][cg * 16 + r] = acc[itile][cg][r];
    }
    __syncthreads();
    if (jh == 0) {
        float gm = gamma[0];
#pragma unroll
        for (int itile = 0; itile < 2; ++itile)
#pragma unroll
            for (int cg = 0; cg < 2; ++cg)
#pragma unroll
                for (int r = 0; r < 16; ++r) {
                    int c = c0 + cg * 32 + (r & 3) + 8 * (r >> 2) + 4 * h;
                    int i = i0 + itile * 32 + il;
                    size_t idx = ((size_t)b * Cx + c) * Nx + i;
                    out[idx] = x[idx] +
                        gm * (acc[itile][cg][r] + red[itile][lane][cg * 16 + r]);
                }
    }
}

// ---------------------------------------------------------------------------
extern "C" void kernel_launch(void* const* d_in, const int* in_sizes, int n_in,
                              void* d_out, int out_size, void* d_ws, size_t ws_size,
                              hipStream_t stream) {
    const float* x     = (const float*)d_in[0];
    const float* Wq    = (const float*)d_in[1];
    const float* bq    = (const float*)d_in[2];
    const float* Wk    = (const float*)d_in[3];
    const float* bk    = (const float*)d_in[4];
    const float* Wv    = (const float*)d_in[5];
    const float* bv    = (const float*)d_in[6];
    const float* gamma = (const float*)d_in[7];
    float* out = (float*)d_out;

    const size_t QK = (size_t)Bx * Nx * Dx;
    const size_t VN = (size_t)Bx * Cx * Nx;
    f16* qhi = (f16*)d_ws;
    f16* qlo = qhi + QK;
    f16* khi = qlo + QK;
    f16* klo = khi + QK;
    f16* vhi = klo + QK;
    f16* vlo = vhi + VN;
    float* s = (float*)(vlo + VN);

    qk_proj  <<<Bx * 4 * 9,     256, 0, stream>>>(x, Wq, bq, Wk, bk, qhi, qlo, khi, klo);
    v_proj   <<<Bx * (Nx / 16), 256, 0, stream>>>(x, Wv, bv, vhi, vlo);
    col_stats<<<Bx * 72,        256, 0, stream>>>(qhi, qlo, khi, klo, s);
    attn_out <<<Bx * 36 * 4,    128, 0, stream>>>(qhi, qlo, khi, klo, vhi, vlo, s, x, gamma, out);
}